// Round 1
// baseline (195.063 us; speedup 1.0000x reference)
//
#include <hip/hip_runtime.h>
#include <math.h>

// Problem constants
#define T_LEN   500
#define C_CH    128
#define DM      128     // D_MODEL
#define N_OCC   21
#define KSZ     9
#define N_OUT   40

__device__ __forceinline__ float selu_f(float x) {
    const float lam = 1.0507009873554805f;
    const float la  = 1.7580993408473766f;   // lam * alpha
    float e   = __expf(x);
    float neg = fmaf(la, e, -la);            // lam*alpha*(exp(x)-1)
    return x > 0.f ? lam * x : neg;
}

// ---------------------------------------------------------------------------
// Transpose wq (L, D, O, K) -> wqT[(l*21+o)*9+k][D]  (coalesced-by-D loads)
// ---------------------------------------------------------------------------
__global__ void wq_transpose(const float* __restrict__ wq, float* __restrict__ wqT) {
    int idx = blockIdx.x * 256 + threadIdx.x;          // 2*21*9*128 = 48384
    if (idx >= 2 * N_OCC * KSZ * DM) return;
    int D  = idx & 127;
    int r  = idx >> 7;                                 // (l*21+o)*9+k
    int k  = r % KSZ;
    int r2 = r / KSZ;
    int o  = r2 % N_OCC;
    int l  = r2 / N_OCC;
    wqT[idx] = wq[(((size_t)l * DM + D) * N_OCC + o) * KSZ + k];
}

// ---------------------------------------------------------------------------
// Q conv: Qt[b][t][D] = selu( sum_{o,k} x[b, occ[o], t+k-4] * wq[l,D,o,k] )
// grid (50, 8), block 128 (one thread per D), 10 t per block
// ---------------------------------------------------------------------------
#define ATCH 10
__global__ __launch_bounds__(128) void qconv_kernel(
    const float* __restrict__ xin, const int* __restrict__ occ,
    const float* __restrict__ wqT, float* __restrict__ qt, int l)
{
    const int b  = blockIdx.y;
    const int t0 = blockIdx.x * ATCH;
    const int D  = threadIdx.x;
    __shared__ float xo[N_OCC][ATCH + 8];
    for (int i = threadIdx.x; i < N_OCC * (ATCH + 8); i += 128) {
        int o = i / (ATCH + 8), j = i % (ATCH + 8);
        int tg = t0 + j - 4;
        xo[o][j] = (tg >= 0 && tg < T_LEN)
                     ? xin[((size_t)b * C_CH + occ[o]) * T_LEN + tg] : 0.f;
    }
    __syncthreads();

    float acc[ATCH];
#pragma unroll
    for (int tt = 0; tt < ATCH; ++tt) acc[tt] = 0.f;

    for (int o = 0; o < N_OCC; ++o) {
        float xr[ATCH + 8];
#pragma unroll
        for (int j = 0; j < ATCH + 8; ++j) xr[j] = xo[o][j];
#pragma unroll
        for (int k = 0; k < KSZ; ++k) {
            float w = wqT[(((size_t)l * N_OCC + o) * KSZ + k) * DM + D];
#pragma unroll
            for (int tt = 0; tt < ATCH; ++tt)
                acc[tt] = fmaf(xr[tt + k], w, acc[tt]);
        }
    }
#pragma unroll
    for (int tt = 0; tt < ATCH; ++tt)
        qt[((size_t)b * T_LEN + t0 + tt) * DM + D] = selu_f(acc[tt]);
}

// ---------------------------------------------------------------------------
// Fused K/V conv + gates + weighted-V + proj + residual for one (b,c) row.
// grid (128, 8), block 256, 2 t per thread. K/V never materialized.
// ---------------------------------------------------------------------------
#define TCH 2
__global__ __launch_bounds__(256) void fused_layer(
    const float* __restrict__ xin, const float* __restrict__ qt,
    const float* __restrict__ wk, const float* __restrict__ wv,
    const float* __restrict__ wproj, float* __restrict__ xout, int l)
{
    const int c = blockIdx.x, b = blockIdx.y;
    __shared__ float xrow[T_LEN + 8];
    const float* xp = xin + ((size_t)(b * C_CH + c)) * T_LEN;
    for (int i = threadIdx.x; i < T_LEN + 8; i += 256) {
        int tg = i - 4;
        xrow[i] = (tg >= 0 && tg < T_LEN) ? xp[tg] : 0.f;
    }
    __syncthreads();

    const int t0 = threadIdx.x * TCH;
    if (t0 >= T_LEN) return;                 // threads 250..255 idle

    float xw[TCH + 8];
#pragma unroll
    for (int j = 0; j < TCH + 8; ++j) xw[j] = xrow[t0 + j];

    // block-uniform weight bases -> scalar loads
    const float* wkp = wk + ((size_t)l * C_CH * DM + (size_t)c * DM) * KSZ;
    const float* wvp = wv + ((size_t)l * C_CH * DM + (size_t)c * DM) * KSZ;
    const float* wpp = wproj + ((size_t)l * C_CH + c) * DM;
    const float4* qp4 = reinterpret_cast<const float4*>(
        qt + ((size_t)b * T_LEN + t0) * DM);

    float qk[8][TCH];
#pragma unroll
    for (int h = 0; h < 8; ++h)
#pragma unroll
        for (int tt = 0; tt < TCH; ++tt) qk[h][tt] = 0.f;

    // pass 1: K conv + Q.K accumulate per head
#pragma unroll 2
    for (int D4 = 0; D4 < 32; ++D4) {
        float4 q0 = qp4[D4];
        float4 q1 = qp4[32 + D4];
        const int h = D4 >> 2;
#pragma unroll
        for (int j = 0; j < 4; ++j) {
            const int D = D4 * 4 + j;
            const float* w = wkp + D * KSZ;
            float a0 = xw[0] * w[0];
            float a1 = xw[1] * w[0];
#pragma unroll
            for (int k = 1; k < KSZ; ++k) {
                a0 = fmaf(xw[k],     w[k], a0);
                a1 = fmaf(xw[k + 1], w[k], a1);
            }
            float kv0 = selu_f(a0), kv1 = selu_f(a1);
            qk[h][0] = fmaf((&q0.x)[j], kv0, qk[h][0]);
            qk[h][1] = fmaf((&q1.x)[j], kv1, qk[h][1]);
        }
    }

    float g[8][TCH];
#pragma unroll
    for (int h = 0; h < 8; ++h)
#pragma unroll
        for (int tt = 0; tt < TCH; ++tt)
            g[h][tt] = selu_f(qk[h][tt] * 0.25f);   // scale = d^-0.5 = 0.25

    // pass 2: V conv, gate, project
    float acc[TCH];
#pragma unroll
    for (int tt = 0; tt < TCH; ++tt) acc[tt] = 0.f;
#pragma unroll 2
    for (int D = 0; D < 128; ++D) {
        const float* w = wvp + D * KSZ;
        const float wpd = wpp[D];
        const int h = D >> 4;
        float a0 = xw[0] * w[0];
        float a1 = xw[1] * w[0];
#pragma unroll
        for (int k = 1; k < KSZ; ++k) {
            a0 = fmaf(xw[k],     w[k], a0);
            a1 = fmaf(xw[k + 1], w[k], a1);
        }
        acc[0] = fmaf(g[h][0] * selu_f(a0), wpd, acc[0]);
        acc[1] = fmaf(g[h][1] * selu_f(a1), wpd, acc[1]);
    }

    float* xo = xout + ((size_t)(b * C_CH + c)) * T_LEN + t0;
    const float rs = 0.70710678118654752f;
#pragma unroll
    for (int tt = 0; tt < TCH; ++tt)
        xo[tt] = (xw[tt + 4] + selu_f(acc[tt])) * rs;
}

// ---------------------------------------------------------------------------
// Head: logits[b,o] = b_head[o] + sum_i x[b,i] * w_head[o,i]   (i < 64000)
// grid (40, 8), block 256
// ---------------------------------------------------------------------------
__global__ __launch_bounds__(256) void head_kernel(
    const float* __restrict__ x, const float* __restrict__ wh,
    const float* __restrict__ bh, float* __restrict__ out)
{
    const int o = blockIdx.x;
    const int b = blockIdx.y;
    const float2* xp = reinterpret_cast<const float2*>(x + (size_t)b * C_CH * T_LEN);
    const float2* wp = reinterpret_cast<const float2*>(wh + (size_t)o * C_CH * T_LEN);
    float s = 0.f;
    for (int i = threadIdx.x; i < C_CH * T_LEN / 2; i += 256) {
        float2 xv = xp[i], wv = wp[i];
        s = fmaf(xv.x, wv.x, s);
        s = fmaf(xv.y, wv.y, s);
    }
#pragma unroll
    for (int off = 32; off > 0; off >>= 1) s += __shfl_down(s, off);
    __shared__ float red[4];
    const int lane = threadIdx.x & 63, wid = threadIdx.x >> 6;
    if (lane == 0) red[wid] = s;
    __syncthreads();
    if (threadIdx.x == 0)
        out[b * N_OUT + o] = red[0] + red[1] + red[2] + red[3] + bh[o];
}

// ---------------------------------------------------------------------------
extern "C" void kernel_launch(void* const* d_in, const int* in_sizes, int n_in,
                              void* d_out, int out_size, void* d_ws, size_t ws_size,
                              hipStream_t stream) {
    const float* x     = (const float*)d_in[0];
    const int*   occ   = (const int*)  d_in[1];
    const float* wq    = (const float*)d_in[2];
    const float* wk    = (const float*)d_in[3];
    const float* wv    = (const float*)d_in[4];
    const float* wproj = (const float*)d_in[5];
    const float* wh    = (const float*)d_in[6];
    const float* bh    = (const float*)d_in[7];
    float* out = (float*)d_out;

    float* ws  = (float*)d_ws;
    float* wqT = ws;                       // 2*21*9*128      = 48384
    float* qtb = wqT + 2 * N_OCC * KSZ * DM;
    float* xb0 = qtb + (size_t)8 * T_LEN * DM;   // 512000
    float* xb1 = xb0 + (size_t)8 * C_CH * T_LEN; // 512000

    wq_transpose<<<dim3(189), 256, 0, stream>>>(wq, wqT);

    // layer 0 (reads the input x directly)
    qconv_kernel<<<dim3(50, 8), 128, 0, stream>>>(x, occ, wqT, qtb, 0);
    fused_layer <<<dim3(128, 8), 256, 0, stream>>>(x, qtb, wk, wv, wproj, xb0, 0);

    // layer 1
    qconv_kernel<<<dim3(50, 8), 128, 0, stream>>>(xb0, occ, wqT, qtb, 1);
    fused_layer <<<dim3(128, 8), 256, 0, stream>>>(xb0, qtb, wk, wv, wproj, xb1, 1);

    head_kernel <<<dim3(N_OUT, 8), 256, 0, stream>>>(xb1, wh, bh, out);
}

// Round 2
// 182.408 us; speedup vs baseline: 1.0694x; 1.0694x over previous
//
#include <hip/hip_runtime.h>
#include <math.h>

// Problem constants
#define T_LEN   500
#define C_CH    128
#define DM      128     // D_MODEL
#define N_OCC   21
#define KSZ     9
#define N_OUT   40

__device__ __forceinline__ float selu_f(float x) {
    const float lam = 1.0507009873554805f;
    const float la  = 1.7580993408473766f;   // lam * alpha
    float e   = __expf(x);
    float neg = fmaf(la, e, -la);            // lam*alpha*(exp(x)-1)
    return x > 0.f ? lam * x : neg;
}

// ---------------------------------------------------------------------------
// Transpose wq (L, D, O, K) -> wqT[(l*21+o)*9+k][D]  (coalesced-by-D loads)
// ---------------------------------------------------------------------------
__global__ void wq_transpose(const float* __restrict__ wq, float* __restrict__ wqT) {
    int idx = blockIdx.x * 256 + threadIdx.x;          // 2*21*9*128 = 48384
    if (idx >= 2 * N_OCC * KSZ * DM) return;
    int D  = idx & 127;
    int r  = idx >> 7;                                 // (l*21+o)*9+k
    int k  = r % KSZ;
    int r2 = r / KSZ;
    int o  = r2 % N_OCC;
    int l  = r2 / N_OCC;
    wqT[idx] = wq[(((size_t)l * DM + D) * N_OCC + o) * KSZ + k];
}

// ---------------------------------------------------------------------------
// Q conv: Qt[b][t][D] = selu( sum_{o,k} x[b, occ[o], t+k-4] * wq[l,D,o,k] )
// grid (125, 8), block 128 (one thread per D), 4 t per block
// ---------------------------------------------------------------------------
#define ATCH 4
__global__ __launch_bounds__(128) void qconv_kernel(
    const float* __restrict__ xin, const int* __restrict__ occ,
    const float* __restrict__ wqT, float* __restrict__ qt, int l)
{
    const int b  = blockIdx.y;
    const int t0 = blockIdx.x * ATCH;
    const int D  = threadIdx.x;
    __shared__ float xo[N_OCC][ATCH + 8];
    for (int i = threadIdx.x; i < N_OCC * (ATCH + 8); i += 128) {
        int o = i / (ATCH + 8), j = i % (ATCH + 8);
        int tg = t0 + j - 4;
        xo[o][j] = (tg >= 0 && tg < T_LEN)
                     ? xin[((size_t)b * C_CH + occ[o]) * T_LEN + tg] : 0.f;
    }
    __syncthreads();

    float acc[ATCH];
#pragma unroll
    for (int tt = 0; tt < ATCH; ++tt) acc[tt] = 0.f;

    for (int o = 0; o < N_OCC; ++o) {
        float xr[ATCH + 8];
#pragma unroll
        for (int j = 0; j < ATCH + 8; ++j) xr[j] = xo[o][j];
#pragma unroll
        for (int k = 0; k < KSZ; ++k) {
            float w = wqT[(((size_t)l * N_OCC + o) * KSZ + k) * DM + D];
#pragma unroll
            for (int tt = 0; tt < ATCH; ++tt)
                acc[tt] = fmaf(xr[tt + k], w, acc[tt]);
        }
    }
#pragma unroll
    for (int tt = 0; tt < ATCH; ++tt)
        qt[((size_t)b * T_LEN + t0 + tt) * DM + D] = selu_f(acc[tt]);
}

// ---------------------------------------------------------------------------
// Fused K/V conv + gates + weighted-V + proj + residual for one (b,c) row.
// grid (128, 8), block 512, 1 t per thread (500 active). K/V never
// materialized. 8192 waves total -> 32 waves/CU theoretical.
// ---------------------------------------------------------------------------
__global__ __launch_bounds__(512) void fused_layer(
    const float* __restrict__ xin, const float* __restrict__ qt,
    const float* __restrict__ wk, const float* __restrict__ wv,
    const float* __restrict__ wproj, float* __restrict__ xout, int l)
{
    const int c = blockIdx.x, b = blockIdx.y;
    __shared__ float xrow[T_LEN + 8];
    const float* xp = xin + ((size_t)(b * C_CH + c)) * T_LEN;
    for (int i = threadIdx.x; i < T_LEN + 8; i += 512) {
        int tg = i - 4;
        xrow[i] = (tg >= 0 && tg < T_LEN) ? xp[tg] : 0.f;
    }
    __syncthreads();

    const int t = threadIdx.x;
    if (t >= T_LEN) return;                 // threads 500..511 idle

    float xw[KSZ];
#pragma unroll
    for (int j = 0; j < KSZ; ++j) xw[j] = xrow[t + j];

    // block-uniform weight bases -> scalar loads
    const float* wkp = wk + ((size_t)l * C_CH * DM + (size_t)c * DM) * KSZ;
    const float* wvp = wv + ((size_t)l * C_CH * DM + (size_t)c * DM) * KSZ;
    const float* wpp = wproj + ((size_t)l * C_CH + c) * DM;
    const float4* qp4 = reinterpret_cast<const float4*>(
        qt + ((size_t)b * T_LEN + t) * DM);

    float qk[8];
#pragma unroll
    for (int h = 0; h < 8; ++h) qk[h] = 0.f;

    // pass 1: K conv + Q.K accumulate per head
#pragma unroll 4
    for (int D4 = 0; D4 < 32; ++D4) {
        float4 q0 = qp4[D4];
        const int h = D4 >> 2;
#pragma unroll
        for (int j = 0; j < 4; ++j) {
            const int D = D4 * 4 + j;
            const float* w = wkp + D * KSZ;
            float a0 = xw[0] * w[0];
#pragma unroll
            for (int k = 1; k < KSZ; ++k)
                a0 = fmaf(xw[k], w[k], a0);
            qk[h] = fmaf((&q0.x)[j], selu_f(a0), qk[h]);
        }
    }

    float g[8];
#pragma unroll
    for (int h = 0; h < 8; ++h)
        g[h] = selu_f(qk[h] * 0.25f);       // scale = d^-0.5 = 0.25

    // pass 2: V conv, per-head partial, then gate once per head
    float acc = 0.f;
#pragma unroll
    for (int h = 0; h < 8; ++h) {
        float ah = 0.f;
#pragma unroll 4
        for (int dd = 0; dd < 16; ++dd) {
            const int D = h * 16 + dd;
            const float* w = wvp + D * KSZ;
            float a0 = xw[0] * w[0];
#pragma unroll
            for (int k = 1; k < KSZ; ++k)
                a0 = fmaf(xw[k], w[k], a0);
            ah = fmaf(selu_f(a0), wpp[D], ah);
        }
        acc = fmaf(g[h], ah, acc);
    }

    const float rs = 0.70710678118654752f;
    xout[((size_t)(b * C_CH + c)) * T_LEN + t] = (xw[4] + selu_f(acc)) * rs;
}

// ---------------------------------------------------------------------------
// Head stage 1: partial[o][ch][b] = sum over chunk of x[b,i]*w_head[o,i]
// grid (40, 8 chunks), block 256. w_head row fetched once per chunk (not 8x).
// ---------------------------------------------------------------------------
#define NCHUNK 8
#define CHUNK  (C_CH * T_LEN / NCHUNK)      // 8000
__global__ __launch_bounds__(256) void head_partial(
    const float* __restrict__ x, const float* __restrict__ wh,
    float* __restrict__ part)
{
    const int o  = blockIdx.x;
    const int ch = blockIdx.y;
    const int base = ch * CHUNK;
    const float4* wp = reinterpret_cast<const float4*>(wh + (size_t)o * (C_CH * T_LEN) + base);

    float acc[8];
#pragma unroll
    for (int b = 0; b < 8; ++b) acc[b] = 0.f;

    for (int i = threadIdx.x; i < CHUNK / 4; i += 256) {
        float4 w4 = wp[i];
#pragma unroll
        for (int b = 0; b < 8; ++b) {
            float4 x4 = reinterpret_cast<const float4*>(
                x + (size_t)b * (C_CH * T_LEN) + base)[i];
            acc[b] = fmaf(x4.x, w4.x, acc[b]);
            acc[b] = fmaf(x4.y, w4.y, acc[b]);
            acc[b] = fmaf(x4.z, w4.z, acc[b]);
            acc[b] = fmaf(x4.w, w4.w, acc[b]);
        }
    }

#pragma unroll
    for (int b = 0; b < 8; ++b)
#pragma unroll
        for (int off = 32; off > 0; off >>= 1)
            acc[b] += __shfl_down(acc[b], off);

    __shared__ float red[4][8];
    const int lane = threadIdx.x & 63, wid = threadIdx.x >> 6;
    if (lane == 0)
#pragma unroll
        for (int b = 0; b < 8; ++b) red[wid][b] = acc[b];
    __syncthreads();
    if (threadIdx.x < 8) {
        int b = threadIdx.x;
        part[((size_t)o * NCHUNK + ch) * 8 + b]
            = red[0][b] + red[1][b] + red[2][b] + red[3][b];
    }
}

// Head stage 2: out[b,o] = b_head[o] + sum_ch part[o][ch][b].  1 block, 320 thr
__global__ __launch_bounds__(320) void head_final(
    const float* __restrict__ part, const float* __restrict__ bh,
    float* __restrict__ out)
{
    int i = threadIdx.x;
    if (i >= N_OUT * 8) return;
    int o = i >> 3, b = i & 7;
    float s = bh[o];
#pragma unroll
    for (int ch = 0; ch < NCHUNK; ++ch)
        s += part[((size_t)o * NCHUNK + ch) * 8 + b];
    out[b * N_OUT + o] = s;
}

// ---------------------------------------------------------------------------
extern "C" void kernel_launch(void* const* d_in, const int* in_sizes, int n_in,
                              void* d_out, int out_size, void* d_ws, size_t ws_size,
                              hipStream_t stream) {
    const float* x     = (const float*)d_in[0];
    const int*   occ   = (const int*)  d_in[1];
    const float* wq    = (const float*)d_in[2];
    const float* wk    = (const float*)d_in[3];
    const float* wv    = (const float*)d_in[4];
    const float* wproj = (const float*)d_in[5];
    const float* wh    = (const float*)d_in[6];
    const float* bh    = (const float*)d_in[7];
    float* out = (float*)d_out;

    float* ws  = (float*)d_ws;
    float* wqT = ws;                              // 48384
    float* qtb = wqT + 2 * N_OCC * KSZ * DM;      // 512000
    float* xb0 = qtb + (size_t)8 * T_LEN * DM;    // 512000
    float* xb1 = xb0 + (size_t)8 * C_CH * T_LEN;  // 512000
    float* hp  = xb1 + (size_t)8 * C_CH * T_LEN;  // 40*8*8 = 2560

    wq_transpose<<<dim3(189), 256, 0, stream>>>(wq, wqT);

    // layer 0 (reads the input x directly)
    qconv_kernel<<<dim3(125, 8), 128, 0, stream>>>(x, occ, wqT, qtb, 0);
    fused_layer <<<dim3(128, 8), 512, 0, stream>>>(x, qtb, wk, wv, wproj, xb0, 0);

    // layer 1
    qconv_kernel<<<dim3(125, 8), 128, 0, stream>>>(xb0, occ, wqT, qtb, 1);
    fused_layer <<<dim3(128, 8), 512, 0, stream>>>(xb0, qtb, wk, wv, wproj, xb1, 1);

    head_partial<<<dim3(N_OUT, NCHUNK), 256, 0, stream>>>(xb1, wh, hp);
    head_final  <<<dim3(1), 320, 0, stream>>>(hp, bh, out);
}

// Round 3
// 144.286 us; speedup vs baseline: 1.3519x; 1.2642x over previous
//
#include <hip/hip_runtime.h>
#include <math.h>

// Problem constants
#define T_LEN   500
#define C_CH    128
#define DM      128     // D_MODEL
#define N_OCC   21
#define KSZ     9
#define N_OUT   40

typedef _Float16 f16x8 __attribute__((ext_vector_type(8)));
typedef float    f32x16 __attribute__((ext_vector_type(16)));

__device__ __forceinline__ float selu_f(float x) {
    const float lam = 1.0507009873554805f;
    const float la  = 1.7580993408473766f;   // lam * alpha
    float e   = __expf(x);
    float neg = fmaf(la, e, -la);            // lam*alpha*(exp(x)-1)
    return x > 0.f ? lam * x : neg;
}

// ---------------------------------------------------------------------------
// Transpose wq (L, D, O, K) -> wqT[(l*21+o)*9+k][D]  (coalesced-by-D loads)
// ---------------------------------------------------------------------------
__global__ void wq_transpose(const float* __restrict__ wq, float* __restrict__ wqT) {
    int idx = blockIdx.x * 256 + threadIdx.x;          // 2*21*9*128 = 48384
    if (idx >= 2 * N_OCC * KSZ * DM) return;
    int D  = idx & 127;
    int r  = idx >> 7;                                 // (l*21+o)*9+k
    int k  = r % KSZ;
    int r2 = r / KSZ;
    int o  = r2 % N_OCC;
    int l  = r2 / N_OCC;
    wqT[idx] = wq[(((size_t)l * DM + D) * N_OCC + o) * KSZ + k];
}

// ---------------------------------------------------------------------------
// Q conv: Qt[b][t][D] = selu( sum_{o,k} x[b, occ[o], t+k-4] * wq[l,D,o,k] )
// grid (125, 8), block 128 (one thread per D), 4 t per block
// ---------------------------------------------------------------------------
#define ATCH 4
__global__ __launch_bounds__(128) void qconv_kernel(
    const float* __restrict__ xin, const int* __restrict__ occ,
    const float* __restrict__ wqT, float* __restrict__ qt, int l)
{
    const int b  = blockIdx.y;
    const int t0 = blockIdx.x * ATCH;
    const int D  = threadIdx.x;
    __shared__ float xo[N_OCC][ATCH + 8];
    for (int i = threadIdx.x; i < N_OCC * (ATCH + 8); i += 128) {
        int o = i / (ATCH + 8), j = i % (ATCH + 8);
        int tg = t0 + j - 4;
        xo[o][j] = (tg >= 0 && tg < T_LEN)
                     ? xin[((size_t)b * C_CH + occ[o]) * T_LEN + tg] : 0.f;
    }
    __syncthreads();

    float acc[ATCH];
#pragma unroll
    for (int tt = 0; tt < ATCH; ++tt) acc[tt] = 0.f;

    for (int o = 0; o < N_OCC; ++o) {
        float xr[ATCH + 8];
#pragma unroll
        for (int j = 0; j < ATCH + 8; ++j) xr[j] = xo[o][j];
#pragma unroll
        for (int k = 0; k < KSZ; ++k) {
            float w = wqT[(((size_t)l * N_OCC + o) * KSZ + k) * DM + D];
#pragma unroll
            for (int tt = 0; tt < ATCH; ++tt)
                acc[tt] = fmaf(xr[tt + k], w, acc[tt]);
        }
    }
#pragma unroll
    for (int tt = 0; tt < ATCH; ++tt)
        qt[((size_t)b * T_LEN + t0 + tt) * DM + D] = selu_f(acc[tt]);
}

// ---------------------------------------------------------------------------
// MFMA fused layer. Block = (c, b), 256 threads = 4 waves.
// Per wave: 4 t-tiles of 32. K/V conv via mfma_f32_32x32x16_f16:
//   A = weight rows (M=32 D's, K=16 taps padded from 9), B = x window
//   (K=16 taps, N=32 t's). C layout: col = lane&31 = t,
//   row = (reg&3) + 8*(reg>>2) + 4*(lane>>5)  (D within the 32-chunk).
// A and B are filled with the SAME k-slot assignment phi(hi,j)=8*hi+j, so
// the contraction is correct for any internal hardware k-ordering.
// selu / QK / PV stay on VALU, entirely in registers.
// ---------------------------------------------------------------------------
__global__ __launch_bounds__(256) void fused_layer(
    const float* __restrict__ xin, const float* __restrict__ qt,
    const float* __restrict__ wk, const float* __restrict__ wv,
    const float* __restrict__ wproj, float* __restrict__ xout, int l)
{
    const int c = blockIdx.x, b = blockIdx.y;
    const int tid  = threadIdx.x;
    const int wave = tid >> 6;
    const int lane = tid & 63;
    const int tcol = lane & 31;
    const int hi   = lane >> 5;

    __shared__ float xrow[544];
    const float* xp = xin + ((size_t)(b * C_CH + c)) * T_LEN;
    for (int i = tid; i < 544; i += 256) {
        int tg = i - 4;
        xrow[i] = (tg >= 0 && tg < T_LEN) ? xp[tg] : 0.f;
    }
    __syncthreads();

    // A fragments (per-lane): D = ch*32 + tcol; k-slots phi = 8*hi + j
    f16x8 ak[4], av[4];
#pragma unroll
    for (int ch = 0; ch < 4; ++ch) {
        const int D = ch * 32 + tcol;
        const float* wkp = wk + (((size_t)l * C_CH * DM + (size_t)c * DM + D) * KSZ);
        const float* wvp = wv + (((size_t)l * C_CH * DM + (size_t)c * DM + D) * KSZ);
        if (hi == 0) {
#pragma unroll
            for (int j = 0; j < 8; ++j) {          // k = 0..7
                ak[ch][j] = (_Float16)wkp[j];
                av[ch][j] = (_Float16)wvp[j];
            }
        } else {
            ak[ch][0] = (_Float16)wkp[8];          // k = 8
            av[ch][0] = (_Float16)wvp[8];
#pragma unroll
            for (int j = 1; j < 8; ++j) {          // k = 9..15 -> zero pad
                ak[ch][j] = (_Float16)0.f;
                av[ch][j] = (_Float16)0.f;
            }
        }
    }

    const float4* wp4p = reinterpret_cast<const float4*>(
        wproj + ((size_t)l * C_CH + c) * DM);

#pragma unroll 1
    for (int ti = 0; ti < 4; ++ti) {
        const int t0 = wave * 128 + ti * 32;
        const int t  = t0 + tcol;                    // this lane's t (may be >=500)
        const int tl = t < T_LEN ? t : (T_LEN - 1);  // clamped for loads

        // B fragment: x window, k-slot phi = 8*hi + j
        f16x8 bfr;
        {
            const int base = t0 + tcol + 8 * hi;     // xrow idx = t + k (xrow holds x[i-4])
#pragma unroll
            for (int j = 0; j < 8; ++j) bfr[j] = (_Float16)xrow[base + j];
        }

        const float4* qp = reinterpret_cast<const float4*>(
            qt + ((size_t)b * T_LEN + tl) * DM);

        float qk[8];
#pragma unroll
        for (int h = 0; h < 8; ++h) qk[h] = 0.f;

        // pass 1: K conv (MFMA) + selu + per-head Q.K partials
#pragma unroll
        for (int ch = 0; ch < 4; ++ch) {
            f32x16 acc;
#pragma unroll
            for (int j = 0; j < 16; ++j) acc[j] = 0.f;
            acc = __builtin_amdgcn_mfma_f32_32x32x16_f16(ak[ch], bfr, acc, 0, 0, 0);
            float pA = 0.f, pB = 0.f;
#pragma unroll
            for (int I = 0; I < 4; ++I) {            // reg group: D = ch*32 + 8I + 4hi + i2
                float4 q4 = qp[ch * 8 + 2 * I + hi];
#pragma unroll
                for (int i2 = 0; i2 < 4; ++i2) {
                    float kv = selu_f(acc[4 * I + i2]);
                    float qv = (&q4.x)[i2];
                    if (I < 2) pA = fmaf(qv, kv, pA);
                    else       pB = fmaf(qv, kv, pB);
                }
            }
            qk[ch * 2 + 0] += pA;
            qk[ch * 2 + 1] += pB;
        }

        // gates (each lane holds its hi-half partial; combine across hi)
        float g[8];
#pragma unroll
        for (int h = 0; h < 8; ++h) {
            float full = qk[h] + __shfl_xor(qk[h], 32);
            g[h] = selu_f(full * 0.25f);             // scale = d^-0.5 = 0.25
        }

        // pass 2: V conv (MFMA) + selu + wproj-weighted per-head sums
        float outp = 0.f;
#pragma unroll
        for (int ch = 0; ch < 4; ++ch) {
            f32x16 acc;
#pragma unroll
            for (int j = 0; j < 16; ++j) acc[j] = 0.f;
            acc = __builtin_amdgcn_mfma_f32_32x32x16_f16(av[ch], bfr, acc, 0, 0, 0);
            float sA = 0.f, sB = 0.f;
#pragma unroll
            for (int I = 0; I < 4; ++I) {
                float4 wq4 = wp4p[ch * 8 + 2 * I + hi];
#pragma unroll
                for (int i2 = 0; i2 < 4; ++i2) {
                    float vv = selu_f(acc[4 * I + i2]);
                    if (I < 2) sA = fmaf((&wq4.x)[i2], vv, sA);
                    else       sB = fmaf((&wq4.x)[i2], vv, sB);
                }
            }
            outp = fmaf(g[ch * 2 + 0], sA, outp);
            outp = fmaf(g[ch * 2 + 1], sB, outp);
        }
        float outf = outp + __shfl_xor(outp, 32);

        if (hi == 0 && t < T_LEN) {
            const float rs = 0.70710678118654752f;
            xout[((size_t)(b * C_CH + c)) * T_LEN + t]
                = (xrow[t + 4] + selu_f(outf)) * rs;
        }
    }
}

// ---------------------------------------------------------------------------
// Head stage 1: partial[o][ch][b] = sum over chunk of x[b,i]*w_head[o,i]
// grid (40, 8 chunks), block 256. w_head row fetched once per chunk (not 8x).
// ---------------------------------------------------------------------------
#define NCHUNK 8
#define CHUNK  (C_CH * T_LEN / NCHUNK)      // 8000
__global__ __launch_bounds__(256) void head_partial(
    const float* __restrict__ x, const float* __restrict__ wh,
    float* __restrict__ part)
{
    const int o  = blockIdx.x;
    const int ch = blockIdx.y;
    const int base = ch * CHUNK;
    const float4* wp = reinterpret_cast<const float4*>(wh + (size_t)o * (C_CH * T_LEN) + base);

    float acc[8];
#pragma unroll
    for (int b = 0; b < 8; ++b) acc[b] = 0.f;

    for (int i = threadIdx.x; i < CHUNK / 4; i += 256) {
        float4 w4 = wp[i];
#pragma unroll
        for (int b = 0; b < 8; ++b) {
            float4 x4 = reinterpret_cast<const float4*>(
                x + (size_t)b * (C_CH * T_LEN) + base)[i];
            acc[b] = fmaf(x4.x, w4.x, acc[b]);
            acc[b] = fmaf(x4.y, w4.y, acc[b]);
            acc[b] = fmaf(x4.z, w4.z, acc[b]);
            acc[b] = fmaf(x4.w, w4.w, acc[b]);
        }
    }

#pragma unroll
    for (int b = 0; b < 8; ++b)
#pragma unroll
        for (int off = 32; off > 0; off >>= 1)
            acc[b] += __shfl_down(acc[b], off);

    __shared__ float red[4][8];
    const int lane = threadIdx.x & 63, wid = threadIdx.x >> 6;
    if (lane == 0)
#pragma unroll
        for (int b = 0; b < 8; ++b) red[wid][b] = acc[b];
    __syncthreads();
    if (threadIdx.x < 8) {
        int b = threadIdx.x;
        part[((size_t)o * NCHUNK + ch) * 8 + b]
            = red[0][b] + red[1][b] + red[2][b] + red[3][b];
    }
}

// Head stage 2: out[b,o] = b_head[o] + sum_ch part[o][ch][b].  1 block, 320 thr
__global__ __launch_bounds__(320) void head_final(
    const float* __restrict__ part, const float* __restrict__ bh,
    float* __restrict__ out)
{
    int i = threadIdx.x;
    if (i >= N_OUT * 8) return;
    int o = i >> 3, b = i & 7;
    float s = bh[o];
#pragma unroll
    for (int ch = 0; ch < NCHUNK; ++ch)
        s += part[((size_t)o * NCHUNK + ch) * 8 + b];
    out[b * N_OUT + o] = s;
}

// ---------------------------------------------------------------------------
extern "C" void kernel_launch(void* const* d_in, const int* in_sizes, int n_in,
                              void* d_out, int out_size, void* d_ws, size_t ws_size,
                              hipStream_t stream) {
    const float* x     = (const float*)d_in[0];
    const int*   occ   = (const int*)  d_in[1];
    const float* wq    = (const float*)d_in[2];
    const float* wk    = (const float*)d_in[3];
    const float* wv    = (const float*)d_in[4];
    const float* wproj = (const float*)d_in[5];
    const float* wh    = (const float*)d_in[6];
    const float* bh    = (const float*)d_in[7];
    float* out = (float*)d_out;

    float* ws  = (float*)d_ws;
    float* wqT = ws;                              // 48384
    float* qtb = wqT + 2 * N_OCC * KSZ * DM;      // 512000
    float* xb0 = qtb + (size_t)8 * T_LEN * DM;    // 512000
    float* xb1 = xb0 + (size_t)8 * C_CH * T_LEN;  // 512000
    float* hp  = xb1 + (size_t)8 * C_CH * T_LEN;  // 40*8*8 = 2560

    wq_transpose<<<dim3(189), 256, 0, stream>>>(wq, wqT);

    // layer 0 (reads the input x directly)
    qconv_kernel<<<dim3(125, 8), 128, 0, stream>>>(x, occ, wqT, qtb, 0);
    fused_layer <<<dim3(128, 8), 256, 0, stream>>>(x, qtb, wk, wv, wproj, xb0, 0);

    // layer 1
    qconv_kernel<<<dim3(125, 8), 128, 0, stream>>>(xb0, occ, wqT, qtb, 1);
    fused_layer <<<dim3(128, 8), 256, 0, stream>>>(xb0, qtb, wk, wv, wproj, xb1, 1);

    head_partial<<<dim3(N_OUT, NCHUNK), 256, 0, stream>>>(xb1, wh, hp);
    head_final  <<<dim3(1), 320, 0, stream>>>(hp, bh, out);
}

// Round 4
// 136.036 us; speedup vs baseline: 1.4339x; 1.0606x over previous
//
#include <hip/hip_runtime.h>
#include <math.h>

// Problem constants
#define T_LEN   500
#define C_CH    128
#define DM      128     // D_MODEL
#define N_OCC   21
#define KSZ     9
#define N_OUT   40

typedef _Float16 f16x8 __attribute__((ext_vector_type(8)));
typedef float    f32x16 __attribute__((ext_vector_type(16)));

__device__ __forceinline__ float selu_f(float x) {
    const float lam = 1.0507009873554805f;
    const float la  = 1.7580993408473766f;   // lam * alpha
    float e   = __expf(x);
    float neg = fmaf(la, e, -la);            // lam*alpha*(exp(x)-1)
    return x > 0.f ? lam * x : neg;
}

// ---------------------------------------------------------------------------
// Transpose wq (L, D, O, K) -> wqT[(l*21+o)*9+k][D]  (coalesced-by-D loads)
// ---------------------------------------------------------------------------
__global__ void wq_transpose(const float* __restrict__ wq, float* __restrict__ wqT) {
    int idx = blockIdx.x * 256 + threadIdx.x;          // 2*21*9*128 = 48384
    if (idx >= 2 * N_OCC * KSZ * DM) return;
    int D  = idx & 127;
    int r  = idx >> 7;                                 // (l*21+o)*9+k
    int k  = r % KSZ;
    int r2 = r / KSZ;
    int o  = r2 % N_OCC;
    int l  = r2 / N_OCC;
    wqT[idx] = wq[(((size_t)l * DM + D) * N_OCC + o) * KSZ + k];
}

// ---------------------------------------------------------------------------
// Q conv, writing TRANSPOSED output qtT[b][D][t]:
//   qtT[(b*128+D)*500 + t] = selu( sum_{o,k} x[b, occ[o], t+k-4] * wq[l,D,o,k] )
// grid (125, 8), block 128 (one thread per D), 4 t per block -> float4 store
// ---------------------------------------------------------------------------
#define ATCH 4
__global__ __launch_bounds__(128) void qconv_kernel(
    const float* __restrict__ xin, const int* __restrict__ occ,
    const float* __restrict__ wqT, float* __restrict__ qtT, int l)
{
    const int b  = blockIdx.y;
    const int t0 = blockIdx.x * ATCH;
    const int D  = threadIdx.x;
    __shared__ float xo[N_OCC][ATCH + 8];
    for (int i = threadIdx.x; i < N_OCC * (ATCH + 8); i += 128) {
        int o = i / (ATCH + 8), j = i % (ATCH + 8);
        int tg = t0 + j - 4;
        xo[o][j] = (tg >= 0 && tg < T_LEN)
                     ? xin[((size_t)b * C_CH + occ[o]) * T_LEN + tg] : 0.f;
    }
    __syncthreads();

    float acc[ATCH];
#pragma unroll
    for (int tt = 0; tt < ATCH; ++tt) acc[tt] = 0.f;

    for (int o = 0; o < N_OCC; ++o) {
        float xr[ATCH + 8];
#pragma unroll
        for (int j = 0; j < ATCH + 8; ++j) xr[j] = xo[o][j];
#pragma unroll
        for (int k = 0; k < KSZ; ++k) {
            float w = wqT[(((size_t)l * N_OCC + o) * KSZ + k) * DM + D];
#pragma unroll
            for (int tt = 0; tt < ATCH; ++tt)
                acc[tt] = fmaf(xr[tt + k], w, acc[tt]);
        }
    }
    float4 st;
#pragma unroll
    for (int tt = 0; tt < ATCH; ++tt) (&st.x)[tt] = selu_f(acc[tt]);
    *reinterpret_cast<float4*>(&qtT[((size_t)(b * DM + D)) * T_LEN + t0]) = st;
}

// ---------------------------------------------------------------------------
// MFMA fused layer. Block = (c, b, zi), 256 threads = 4 waves, 2 t-tiles of
// 32 per wave (zi splits t-range in half -> 2048 blocks).
// K/V conv via mfma_f32_32x32x16_f16:
//   A = weight rows (M=32 D's, K=16 taps padded from 9), B = x window
//   (K=16 taps, N=32 t's). C layout: col = lane&31 = t,
//   row = (reg&3) + 8*(reg>>2) + 4*(lane>>5)  (D within the 32-chunk).
// A and B use the SAME k-slot assignment phi(hi,j)=8*hi+j (any bijection ok).
// Q is read from the TRANSPOSED qtT[b][D][t]: per-lane dword loads with
// lanes covering consecutive t -> fully coalesced.
// ---------------------------------------------------------------------------
__global__ __launch_bounds__(256) void fused_layer(
    const float* __restrict__ xin, const float* __restrict__ qtT,
    const float* __restrict__ wk, const float* __restrict__ wv,
    const float* __restrict__ wproj, float* __restrict__ xout, int l)
{
    const int c = blockIdx.x, b = blockIdx.y, zi = blockIdx.z;
    const int tid  = threadIdx.x;
    const int wave = tid >> 6;
    const int lane = tid & 63;
    const int tcol = lane & 31;
    const int hi   = lane >> 5;

    // stage the 272-float x window for this half (t in [zi*256, zi*256+264))
    __shared__ float xs[272];
    const float* xp = xin + ((size_t)(b * C_CH + c)) * T_LEN;
    for (int i = tid; i < 272; i += 256) {
        int tg = zi * 256 + i - 4;
        xs[i] = (tg >= 0 && tg < T_LEN) ? xp[tg] : 0.f;
    }
    __syncthreads();

    // A fragments (per-lane): D = ch*32 + tcol; k-slots phi = 8*hi + j
    f16x8 ak[4], av[4];
#pragma unroll
    for (int ch = 0; ch < 4; ++ch) {
        const int D = ch * 32 + tcol;
        const float* wkp = wk + (((size_t)l * C_CH * DM + (size_t)c * DM + D) * KSZ);
        const float* wvp = wv + (((size_t)l * C_CH * DM + (size_t)c * DM + D) * KSZ);
        if (hi == 0) {
#pragma unroll
            for (int j = 0; j < 8; ++j) {          // k = 0..7
                ak[ch][j] = (_Float16)wkp[j];
                av[ch][j] = (_Float16)wvp[j];
            }
        } else {
            ak[ch][0] = (_Float16)wkp[8];          // k = 8
            av[ch][0] = (_Float16)wvp[8];
#pragma unroll
            for (int j = 1; j < 8; ++j) {          // k = 9..15 -> zero pad
                ak[ch][j] = (_Float16)0.f;
                av[ch][j] = (_Float16)0.f;
            }
        }
    }

    const float4* wp4p = reinterpret_cast<const float4*>(
        wproj + ((size_t)l * C_CH + c) * DM);

#pragma unroll 1
    for (int ti = 0; ti < 2; ++ti) {
        const int loc0 = wave * 64 + ti * 32;        // local t base within window
        const int t    = zi * 256 + loc0 + tcol;     // global t (may be >=500)
        const int tq   = t < T_LEN ? t : (T_LEN - 1);

        // B fragment: x window, k-slot phi = 8*hi + j
        f16x8 bfr;
        {
            const int base = loc0 + tcol + 8 * hi;   // xs idx = local t + k
#pragma unroll
            for (int j = 0; j < 8; ++j) bfr[j] = (_Float16)xs[base + j];
        }

        float qk[8];
#pragma unroll
        for (int h = 0; h < 8; ++h) qk[h] = 0.f;

        // pass 1: K conv (MFMA) + selu + per-head Q.K partials
#pragma unroll
        for (int ch = 0; ch < 4; ++ch) {
            // coalesced Q loads: D = ch*32 + 8I + 4hi + i2, row stride 500
            const float* qTp = qtT + ((size_t)b * DM + ch * 32 + 4 * hi) * T_LEN + tq;
            float qv[16];
#pragma unroll
            for (int I = 0; I < 4; ++I)
#pragma unroll
                for (int i2 = 0; i2 < 4; ++i2)
                    qv[4 * I + i2] = qTp[(size_t)(8 * I + i2) * T_LEN];

            f32x16 acc;
#pragma unroll
            for (int j = 0; j < 16; ++j) acc[j] = 0.f;
            acc = __builtin_amdgcn_mfma_f32_32x32x16_f16(ak[ch], bfr, acc, 0, 0, 0);

            float pA = 0.f, pB = 0.f;
#pragma unroll
            for (int I = 0; I < 4; ++I) {
#pragma unroll
                for (int i2 = 0; i2 < 4; ++i2) {
                    float kv = selu_f(acc[4 * I + i2]);
                    float qvv = qv[4 * I + i2];
                    if (I < 2) pA = fmaf(qvv, kv, pA);
                    else       pB = fmaf(qvv, kv, pB);
                }
            }
            qk[ch * 2 + 0] += pA;
            qk[ch * 2 + 1] += pB;
        }

        // gates (each lane holds its hi-half partial; combine across hi)
        float g[8];
#pragma unroll
        for (int h = 0; h < 8; ++h) {
            float full = qk[h] + __shfl_xor(qk[h], 32);
            g[h] = selu_f(full * 0.25f);             // scale = d^-0.5 = 0.25
        }

        // pass 2: V conv (MFMA) + selu + wproj-weighted per-head sums
        float outp = 0.f;
#pragma unroll
        for (int ch = 0; ch < 4; ++ch) {
            f32x16 acc;
#pragma unroll
            for (int j = 0; j < 16; ++j) acc[j] = 0.f;
            acc = __builtin_amdgcn_mfma_f32_32x32x16_f16(av[ch], bfr, acc, 0, 0, 0);
            float sA = 0.f, sB = 0.f;
#pragma unroll
            for (int I = 0; I < 4; ++I) {
                float4 wq4 = wp4p[ch * 8 + 2 * I + hi];
#pragma unroll
                for (int i2 = 0; i2 < 4; ++i2) {
                    float vv = selu_f(acc[4 * I + i2]);
                    if (I < 2) sA = fmaf((&wq4.x)[i2], vv, sA);
                    else       sB = fmaf((&wq4.x)[i2], vv, sB);
                }
            }
            outp = fmaf(g[ch * 2 + 0], sA, outp);
            outp = fmaf(g[ch * 2 + 1], sB, outp);
        }
        float outf = outp + __shfl_xor(outp, 32);

        if (hi == 0 && t < T_LEN) {
            const float rs = 0.70710678118654752f;
            xout[((size_t)(b * C_CH + c)) * T_LEN + t]
                = (xs[loc0 + tcol + 4] + selu_f(outf)) * rs;
        }
    }
}

// ---------------------------------------------------------------------------
// Head stage 1: partial[o][ch][b] = sum over chunk of x[b,i]*w_head[o,i]
// grid (40, 8 chunks), block 256. w_head row fetched once per chunk (not 8x).
// ---------------------------------------------------------------------------
#define NCHUNK 8
#define CHUNK  (C_CH * T_LEN / NCHUNK)      // 8000
__global__ __launch_bounds__(256) void head_partial(
    const float* __restrict__ x, const float* __restrict__ wh,
    float* __restrict__ part)
{
    const int o  = blockIdx.x;
    const int ch = blockIdx.y;
    const int base = ch * CHUNK;
    const float4* wp = reinterpret_cast<const float4*>(wh + (size_t)o * (C_CH * T_LEN) + base);

    float acc[8];
#pragma unroll
    for (int b = 0; b < 8; ++b) acc[b] = 0.f;

    for (int i = threadIdx.x; i < CHUNK / 4; i += 256) {
        float4 w4 = wp[i];
#pragma unroll
        for (int b = 0; b < 8; ++b) {
            float4 x4 = reinterpret_cast<const float4*>(
                x + (size_t)b * (C_CH * T_LEN) + base)[i];
            acc[b] = fmaf(x4.x, w4.x, acc[b]);
            acc[b] = fmaf(x4.y, w4.y, acc[b]);
            acc[b] = fmaf(x4.z, w4.z, acc[b]);
            acc[b] = fmaf(x4.w, w4.w, acc[b]);
        }
    }

#pragma unroll
    for (int b = 0; b < 8; ++b)
#pragma unroll
        for (int off = 32; off > 0; off >>= 1)
            acc[b] += __shfl_down(acc[b], off);

    __shared__ float red[4][8];
    const int lane = threadIdx.x & 63, wid = threadIdx.x >> 6;
    if (lane == 0)
#pragma unroll
        for (int b = 0; b < 8; ++b) red[wid][b] = acc[b];
    __syncthreads();
    if (threadIdx.x < 8) {
        int b = threadIdx.x;
        part[((size_t)o * NCHUNK + ch) * 8 + b]
            = red[0][b] + red[1][b] + red[2][b] + red[3][b];
    }
}

// Head stage 2: out[b,o] = b_head[o] + sum_ch part[o][ch][b].  1 block, 320 thr
__global__ __launch_bounds__(320) void head_final(
    const float* __restrict__ part, const float* __restrict__ bh,
    float* __restrict__ out)
{
    int i = threadIdx.x;
    if (i >= N_OUT * 8) return;
    int o = i >> 3, b = i & 7;
    float s = bh[o];
#pragma unroll
    for (int ch = 0; ch < NCHUNK; ++ch)
        s += part[((size_t)o * NCHUNK + ch) * 8 + b];
    out[b * N_OUT + o] = s;
}

// ---------------------------------------------------------------------------
extern "C" void kernel_launch(void* const* d_in, const int* in_sizes, int n_in,
                              void* d_out, int out_size, void* d_ws, size_t ws_size,
                              hipStream_t stream) {
    const float* x     = (const float*)d_in[0];
    const int*   occ   = (const int*)  d_in[1];
    const float* wq    = (const float*)d_in[2];
    const float* wk    = (const float*)d_in[3];
    const float* wv    = (const float*)d_in[4];
    const float* wproj = (const float*)d_in[5];
    const float* wh    = (const float*)d_in[6];
    const float* bh    = (const float*)d_in[7];
    float* out = (float*)d_out;

    float* ws  = (float*)d_ws;
    float* wqT = ws;                              // 48384
    float* qtb = wqT + 2 * N_OCC * KSZ * DM;      // 512000 (transposed Q)
    float* xb0 = qtb + (size_t)8 * T_LEN * DM;    // 512000
    float* xb1 = xb0 + (size_t)8 * C_CH * T_LEN;  // 512000
    float* hp  = xb1 + (size_t)8 * C_CH * T_LEN;  // 40*8*8 = 2560

    wq_transpose<<<dim3(189), 256, 0, stream>>>(wq, wqT);

    // layer 0 (reads the input x directly)
    qconv_kernel<<<dim3(125, 8), 128, 0, stream>>>(x, occ, wqT, qtb, 0);
    fused_layer <<<dim3(128, 8, 2), 256, 0, stream>>>(x, qtb, wk, wv, wproj, xb0, 0);

    // layer 1
    qconv_kernel<<<dim3(125, 8), 128, 0, stream>>>(xb0, occ, wqT, qtb, 1);
    fused_layer <<<dim3(128, 8, 2), 256, 0, stream>>>(xb0, qtb, wk, wv, wproj, xb1, 1);

    head_partial<<<dim3(N_OUT, NCHUNK), 256, 0, stream>>>(xb1, wh, hp);
    head_final  <<<dim3(1), 320, 0, stream>>>(hp, bh, out);
}

// Round 5
// 129.017 us; speedup vs baseline: 1.5119x; 1.0544x over previous
//
#include <hip/hip_runtime.h>
#include <math.h>

// Problem constants
#define T_LEN   500
#define C_CH    128
#define DM      128     // D_MODEL
#define N_OCC   21
#define KSZ     9
#define N_OUT   40
#define LOG2E   1.44269504088896340736f

typedef _Float16 f16x8 __attribute__((ext_vector_type(8)));
typedef float    f32x16 __attribute__((ext_vector_type(16)));

__device__ __forceinline__ float exp2_fast(float y) {
#if __has_builtin(__builtin_amdgcn_exp2f)
    return __builtin_amdgcn_exp2f(y);
#else
    return exp2f(y);
#endif
}

// y = x * log2(e)  ->  returns selu(x).  5 VALU ops, exp2 is raw v_exp_f32.
__device__ __forceinline__ float selu2(float y) {
    const float c1 = 0.7282904300f;          // lambda * ln2
    const float la = 1.7580993408473766f;    // lambda * alpha
    float e = exp2_fast(y);
    return y > 0.f ? c1 * y : fmaf(la, e, -la);
}

// ---------------------------------------------------------------------------
// Transpose wq (L,D,O,K) -> wqT[(l*21+o)*9+k][D], scaled by log2e
// ---------------------------------------------------------------------------
__global__ void wq_transpose(const float* __restrict__ wq, float* __restrict__ wqT) {
    int idx = blockIdx.x * 256 + threadIdx.x;          // 2*21*9*128 = 48384
    if (idx >= 2 * N_OCC * KSZ * DM) return;
    int D  = idx & 127;
    int r  = idx >> 7;
    int k  = r % KSZ;
    int r2 = r / KSZ;
    int o  = r2 % N_OCC;
    int l  = r2 / N_OCC;
    wqT[idx] = wq[(((size_t)l * DM + D) * N_OCC + o) * KSZ + k] * LOG2E;
}

// ---------------------------------------------------------------------------
// Pre-pack wk/wv into MFMA A-fragment layout, f16, scaled by log2e:
//   wkh[(((l*128+c)*4+ch)*64+lane)*8 + j] = wk[l, c*128 + ch*32+(lane&31), k=8*(lane>>5)+j]
//   (zero for k >= 9)
// ---------------------------------------------------------------------------
__global__ void wprep_kernel(const float* __restrict__ wk, const float* __restrict__ wv,
                             _Float16* __restrict__ wkh, _Float16* __restrict__ wvh)
{
    int idx = blockIdx.x * 256 + threadIdx.x;          // 2*128*4*64 = 65536
    if (idx >= 2 * C_CH * 4 * 64) return;
    int lane = idx & 63;
    int ch   = (idx >> 6) & 3;
    int c    = (idx >> 8) & 127;
    int l    = idx >> 15;
    int tcol = lane & 31, hi = lane >> 5;
    int D    = ch * 32 + tcol;
    const float* wkp = wk + ((size_t)l * C_CH * DM + (size_t)c * DM + D) * KSZ;
    const float* wvp = wv + ((size_t)l * C_CH * DM + (size_t)c * DM + D) * KSZ;
#pragma unroll
    for (int j = 0; j < 8; ++j) {
        int k = 8 * hi + j;
        wkh[(size_t)idx * 8 + j] = (k < KSZ) ? (_Float16)(wkp[k] * LOG2E) : (_Float16)0.f;
        wvh[(size_t)idx * 8 + j] = (k < KSZ) ? (_Float16)(wvp[k] * LOG2E) : (_Float16)0.f;
    }
}

// ---------------------------------------------------------------------------
// Q conv, writing TILED-TRANSPOSED output qtT2[b][tile][D][t-in-tile(32)]:
//   value = selu( sum_{o,k} x[b, occ[o], t+k-4] * wq[l,D,o,k] )
// grid (125, 8), block 128 (one thread per D), 4 t per block -> float4 store
// (t0 % 32 <= 28, so the 4 t's never cross a 32-tile boundary)
// ---------------------------------------------------------------------------
#define ATCH 4
__global__ __launch_bounds__(128) void qconv_kernel(
    const float* __restrict__ xin, const int* __restrict__ occ,
    const float* __restrict__ wqT, float* __restrict__ qtT2, int l)
{
    const int b  = blockIdx.y;
    const int t0 = blockIdx.x * ATCH;
    const int D  = threadIdx.x;
    __shared__ float xo[N_OCC][ATCH + 8];
    for (int i = threadIdx.x; i < N_OCC * (ATCH + 8); i += 128) {
        int o = i / (ATCH + 8), j = i % (ATCH + 8);
        int tg = t0 + j - 4;
        xo[o][j] = (tg >= 0 && tg < T_LEN)
                     ? xin[((size_t)b * C_CH + occ[o]) * T_LEN + tg] : 0.f;
    }
    __syncthreads();

    float acc[ATCH];
#pragma unroll
    for (int tt = 0; tt < ATCH; ++tt) acc[tt] = 0.f;

    for (int o = 0; o < N_OCC; ++o) {
        float xr[ATCH + 8];
#pragma unroll
        for (int j = 0; j < ATCH + 8; ++j) xr[j] = xo[o][j];
#pragma unroll
        for (int k = 0; k < KSZ; ++k) {
            float w = wqT[(((size_t)l * N_OCC + o) * KSZ + k) * DM + D];
#pragma unroll
            for (int tt = 0; tt < ATCH; ++tt)
                acc[tt] = fmaf(xr[tt + k], w, acc[tt]);
        }
    }
    float4 st;
#pragma unroll
    for (int tt = 0; tt < ATCH; ++tt) (&st.x)[tt] = selu2(acc[tt]);
    const int tile = t0 >> 5, tl = t0 & 31;
    *reinterpret_cast<float4*>(
        &qtT2[((size_t)(b * 16 + tile) * DM + D) * 32 + tl]) = st;
}

// ---------------------------------------------------------------------------
// MFMA fused layer. Block = (c, b, zi), 256 threads = 4 waves, 2 t-tiles of
// 32 per wave. K/V conv via mfma_f32_32x32x16_f16 (K=16 taps padded from 9).
// C layout: col = lane&31 = t, row = (reg&3) + 8*(reg>>2) + 4*(lane>>5) = D.
// A fragments come pre-packed (wkh/wvh, log2e-folded); Q comes from the
// 32-t-tiled qtT2 so all 16 loads per ch share one base + small imm offsets.
// ---------------------------------------------------------------------------
__global__ __launch_bounds__(256) void fused_layer(
    const float* __restrict__ xin, const float* __restrict__ qtT2,
    const f16x8* __restrict__ wkh, const f16x8* __restrict__ wvh,
    const float* __restrict__ wproj, float* __restrict__ xout, int l)
{
    const int c = blockIdx.x, b = blockIdx.y, zi = blockIdx.z;
    const int tid  = threadIdx.x;
    const int wave = tid >> 6;
    const int lane = tid & 63;
    const int tcol = lane & 31;
    const int hi   = lane >> 5;

    // stage the 272-float x window for this half (t in [zi*256-4, zi*256+268))
    __shared__ float xs[272];
    const float* xp = xin + ((size_t)(b * C_CH + c)) * T_LEN;
    for (int i = tid; i < 272; i += 256) {
        int tg = zi * 256 + i - 4;
        xs[i] = (tg >= 0 && tg < T_LEN) ? xp[tg] : 0.f;
    }
    __syncthreads();

    // A fragments: one 16B coalesced load per (tensor, ch)
    const f16x8* wkf = wkh + ((size_t)(l * C_CH + c) * 4) * 64 + lane;
    const f16x8* wvf = wvh + ((size_t)(l * C_CH + c) * 4) * 64 + lane;
    f16x8 ak[4], av[4];
#pragma unroll
    for (int ch = 0; ch < 4; ++ch) {
        ak[ch] = wkf[ch * 64];
        av[ch] = wvf[ch * 64];
    }

    const float4* wp4p = reinterpret_cast<const float4*>(
        wproj + ((size_t)l * C_CH + c) * DM);

#pragma unroll 1
    for (int ti = 0; ti < 2; ++ti) {
        const int loc0 = wave * 64 + ti * 32;        // local t base within window
        const int tile = zi * 8 + wave * 2 + ti;     // global 32-t tile index
        const int t    = zi * 256 + loc0 + tcol;     // this lane's t (may be >=500)

        // B fragment: x window, k-slot phi = 8*hi + j (same phi as A)
        f16x8 bfr;
        {
            const int base = loc0 + tcol + 8 * hi;
#pragma unroll
            for (int j = 0; j < 8; ++j) bfr[j] = (_Float16)xs[base + j];
        }

        float qk[8];
#pragma unroll
        for (int h = 0; h < 8; ++h) qk[h] = 0.f;

        // pass 1: K conv (MFMA) + selu + per-head Q.K partials
#pragma unroll
        for (int ch = 0; ch < 4; ++ch) {
            // Q loads: one base per ch, imm offsets (8I+i2)*128B <= 3456
            const float* qTp = qtT2
                + ((size_t)(b * 16 + tile) * DM + ch * 32 + 4 * hi) * 32 + tcol;
            float qv[16];
#pragma unroll
            for (int I = 0; I < 4; ++I)
#pragma unroll
                for (int i2 = 0; i2 < 4; ++i2)
                    qv[4 * I + i2] = qTp[(8 * I + i2) * 32];

            f32x16 acc;
#pragma unroll
            for (int j = 0; j < 16; ++j) acc[j] = 0.f;
            acc = __builtin_amdgcn_mfma_f32_32x32x16_f16(ak[ch], bfr, acc, 0, 0, 0);

            float pA = 0.f, pB = 0.f;
#pragma unroll
            for (int I = 0; I < 4; ++I) {
#pragma unroll
                for (int i2 = 0; i2 < 4; ++i2) {
                    float kv = selu2(acc[4 * I + i2]);
                    float qvv = qv[4 * I + i2];
                    if (I < 2) pA = fmaf(qvv, kv, pA);
                    else       pB = fmaf(qvv, kv, pB);
                }
            }
            qk[ch * 2 + 0] += pA;
            qk[ch * 2 + 1] += pB;
        }

        // gates (combine hi-half partials; fold 0.25 * log2e into the scale)
        float g[8];
#pragma unroll
        for (int h = 0; h < 8; ++h) {
            float full = qk[h] + __shfl_xor(qk[h], 32);
            g[h] = selu2(full * (0.25f * LOG2E));
        }

        // pass 2: V conv (MFMA) + selu + wproj-weighted per-head sums
        float outp = 0.f;
#pragma unroll
        for (int ch = 0; ch < 4; ++ch) {
            f32x16 acc;
#pragma unroll
            for (int j = 0; j < 16; ++j) acc[j] = 0.f;
            acc = __builtin_amdgcn_mfma_f32_32x32x16_f16(av[ch], bfr, acc, 0, 0, 0);
            float sA = 0.f, sB = 0.f;
#pragma unroll
            for (int I = 0; I < 4; ++I) {
                float4 wq4 = wp4p[ch * 8 + 2 * I + hi];
#pragma unroll
                for (int i2 = 0; i2 < 4; ++i2) {
                    float vv = selu2(acc[4 * I + i2]);
                    if (I < 2) sA = fmaf((&wq4.x)[i2], vv, sA);
                    else       sB = fmaf((&wq4.x)[i2], vv, sB);
                }
            }
            outp = fmaf(g[ch * 2 + 0], sA, outp);
            outp = fmaf(g[ch * 2 + 1], sB, outp);
        }
        float outf = outp + __shfl_xor(outp, 32);

        if (hi == 0 && t < T_LEN) {
            const float rs = 0.70710678118654752f;
            xout[((size_t)(b * C_CH + c)) * T_LEN + t]
                = (xs[loc0 + tcol + 4] + selu2(outf * LOG2E)) * rs;
        }
    }
}

// ---------------------------------------------------------------------------
// Head stage 1: partial[o][ch][b] = sum over chunk of x[b,i]*w_head[o,i]
// grid (40, 8 chunks), block 256.
// ---------------------------------------------------------------------------
#define NCHUNK 8
#define CHUNK  (C_CH * T_LEN / NCHUNK)      // 8000
__global__ __launch_bounds__(256) void head_partial(
    const float* __restrict__ x, const float* __restrict__ wh,
    float* __restrict__ part)
{
    const int o  = blockIdx.x;
    const int ch = blockIdx.y;
    const int base = ch * CHUNK;
    const float4* wp = reinterpret_cast<const float4*>(wh + (size_t)o * (C_CH * T_LEN) + base);

    float acc[8];
#pragma unroll
    for (int b = 0; b < 8; ++b) acc[b] = 0.f;

    for (int i = threadIdx.x; i < CHUNK / 4; i += 256) {
        float4 w4 = wp[i];
#pragma unroll
        for (int b = 0; b < 8; ++b) {
            float4 x4 = reinterpret_cast<const float4*>(
                x + (size_t)b * (C_CH * T_LEN) + base)[i];
            acc[b] = fmaf(x4.x, w4.x, acc[b]);
            acc[b] = fmaf(x4.y, w4.y, acc[b]);
            acc[b] = fmaf(x4.z, w4.z, acc[b]);
            acc[b] = fmaf(x4.w, w4.w, acc[b]);
        }
    }

#pragma unroll
    for (int b = 0; b < 8; ++b)
#pragma unroll
        for (int off = 32; off > 0; off >>= 1)
            acc[b] += __shfl_down(acc[b], off);

    __shared__ float red[4][8];
    const int lane = threadIdx.x & 63, wid = threadIdx.x >> 6;
    if (lane == 0)
#pragma unroll
        for (int b = 0; b < 8; ++b) red[wid][b] = acc[b];
    __syncthreads();
    if (threadIdx.x < 8) {
        int b = threadIdx.x;
        part[((size_t)o * NCHUNK + ch) * 8 + b]
            = red[0][b] + red[1][b] + red[2][b] + red[3][b];
    }
}

// Head stage 2: out[b,o] = b_head[o] + sum_ch part[o][ch][b].  1 block, 320 thr
__global__ __launch_bounds__(320) void head_final(
    const float* __restrict__ part, const float* __restrict__ bh,
    float* __restrict__ out)
{
    int i = threadIdx.x;
    if (i >= N_OUT * 8) return;
    int o = i >> 3, b = i & 7;
    float s = bh[o];
#pragma unroll
    for (int ch = 0; ch < NCHUNK; ++ch)
        s += part[((size_t)o * NCHUNK + ch) * 8 + b];
    out[b * N_OUT + o] = s;
}

// ---------------------------------------------------------------------------
extern "C" void kernel_launch(void* const* d_in, const int* in_sizes, int n_in,
                              void* d_out, int out_size, void* d_ws, size_t ws_size,
                              hipStream_t stream) {
    const float* x     = (const float*)d_in[0];
    const int*   occ   = (const int*)  d_in[1];
    const float* wq    = (const float*)d_in[2];
    const float* wk    = (const float*)d_in[3];
    const float* wv    = (const float*)d_in[4];
    const float* wproj = (const float*)d_in[5];
    const float* wh    = (const float*)d_in[6];
    const float* bh    = (const float*)d_in[7];
    float* out = (float*)d_out;

    float* ws  = (float*)d_ws;
    float* wqT = ws;                                   // 48384 f32
    float* qtb = wqT + 2 * N_OCC * KSZ * DM;           // 8*16*128*32 = 524288 f32
    float* xb0 = qtb + (size_t)8 * 16 * DM * 32;       // 512000 f32
    float* xb1 = xb0 + (size_t)8 * C_CH * T_LEN;       // 512000 f32
    float* hp  = xb1 + (size_t)8 * C_CH * T_LEN;       // 2560 f32
    _Float16* wkh = (_Float16*)(hp + N_OUT * NCHUNK * 8);  // 524288 f16 (16B-aligned)
    _Float16* wvh = wkh + (size_t)2 * C_CH * 4 * 64 * 8;   // 524288 f16

    wq_transpose<<<dim3(189), 256, 0, stream>>>(wq, wqT);
    wprep_kernel<<<dim3(256), 256, 0, stream>>>(wk, wv, wkh, wvh);

    // layer 0 (reads the input x directly)
    qconv_kernel<<<dim3(125, 8), 128, 0, stream>>>(x, occ, wqT, qtb, 0);
    fused_layer <<<dim3(128, 8, 2), 256, 0, stream>>>(
        x, qtb, (const f16x8*)wkh, (const f16x8*)wvh, wproj, xb0, 0);

    // layer 1
    qconv_kernel<<<dim3(125, 8), 128, 0, stream>>>(xb0, occ, wqT, qtb, 1);
    fused_layer <<<dim3(128, 8, 2), 256, 0, stream>>>(
        xb0, qtb, (const f16x8*)wkh, (const f16x8*)wvh, wproj, xb1, 1);

    head_partial<<<dim3(N_OUT, NCHUNK), 256, 0, stream>>>(xb1, wh, hp);
    head_final  <<<dim3(1), 320, 0, stream>>>(hp, bh, out);
}